// Round 11
// baseline (314.820 us; speedup 1.0000x reference)
//
#include <hip/hip_runtime.h>

#define TSTEPS 48
#define OUT_STEPS 24
#define L2E 1.44269504088896340736f
#define ECLAMP 30.0f

typedef short bf16x8 __attribute__((ext_vector_type(8)));
typedef float f32x16 __attribute__((ext_vector_type(16)));
typedef float f32x4 __attribute__((ext_vector_type(4)));
typedef unsigned int u32x4 __attribute__((ext_vector_type(4)));

// RNE bf16 hi + truncated-residual lo (weights; off hot path).
__device__ __forceinline__ void bf_split_rne(float f, short& hi, short& lo) {
    unsigned u = __builtin_bit_cast(unsigned, f);
    unsigned r = u + 0x7FFFu + ((u >> 16) & 1u);
    unsigned short hb = (unsigned short)(r >> 16);
    float hif = __builtin_bit_cast(float, (unsigned)hb << 16);
    float lof = f - hif;
    unsigned short lb = (unsigned short)(__builtin_bit_cast(unsigned, lof) >> 16);
    hi = (short)hb; lo = (short)lb;
}

// Gate pre-scale for exp2: i,f,o -> -log2e; g (gate 2) -> -2*log2e.
__device__ __forceinline__ float gate_scale(int g) {
    return (g == 2) ? (-2.0f * L2E) : (-L2E);
}

// U-frag LDS slot (hi-only): (cell*4+g)*2+c, addr (slot*64+lane)*16B.
__device__ __forceinline__ int uslot(int cell, int g, int c) {
    return (cell * 4 + g) * 2 + c;
}

// Per-lane A4 frags IN REGISTERS (R10-verified; no LDS roundtrip).
// Layout: [wk_hi, wk_lo, b_hi, b_lo, 0,0,0,0], B4 = [x,x,1,1].
__device__ __forceinline__ void make_a4(const float* __restrict__ Wks,
                                        const float* __restrict__ bvs,
                                        int m, int H, bf16x8* a4) {
#pragma unroll
    for (int g = 0; g < 4; ++g) {
        const float s = gate_scale(g);
        short whi, wlo, bhi, blo;
        bf_split_rne(Wks[g * 32 + m] * s, whi, wlo);
        bf_split_rne(bvs[g * 32 + m] * s, bhi, blo);
        bf16x8 a = {whi, wlo, bhi, blo, 0, 0, 0, 0};
        u32x4 z4 = {0u, 0u, 0u, 0u};
        if (H != 0) a = __builtin_bit_cast(bf16x8, z4);
        a4[g] = a;
    }
}

// One LSTM step for 32 batch rows. VERBATIM from R10 (verified 273us /
// 4.88e-4). All operands register-resident; 12 MFMA: per gate A4*B4,
// Ah0*B0, Ah1*B1; h carried as RNE bf16 via cvt_pk.
template <bool NEED_P>
__device__ __forceinline__ float lstm_step32(float x,
    const bf16x8* __restrict__ uf0,   // [4] K-half 0 U-frags (regs)
    const bf16x8* __restrict__ uf1,   // [4] K-half 1 U-frags (regs)
    const bf16x8* __restrict__ a4,    // [4] Wk/b frags (regs)
    u32x4& B0, u32x4& B1,
    float* cs, const f32x4* __restrict__ wq,  // [4] Wd in D-reg order (regs)
    unsigned hmask) {
    // B4 on H==0 lanes: [x_rne, x_rne, 1, 1, 0,0,0,0].
    unsigned xr;
    asm("v_cvt_pk_bf16_f32 %0, %1, %2" : "=v"(xr) : "v"(x), "v"(x));
    unsigned w0 = xr & hmask;
    unsigned w1 = 0x3F803F80u & hmask;
    u32x4 b4u = {w0, w1, 0u, 0u};
    const bf16x8 B4 = __builtin_bit_cast(bf16x8, b4u);
    const bf16x8 b0 = __builtin_bit_cast(bf16x8, B0);
    const bf16x8 b1 = __builtin_bit_cast(bf16x8, B1);
    const f32x16 zero16 = {0,0,0,0,0,0,0,0,0,0,0,0,0,0,0,0};

    f32x16 acc[4];
#pragma unroll
    for (int g = 0; g < 4; ++g) {
        f32x16 a = __builtin_amdgcn_mfma_f32_32x32x16_bf16(a4[g], B4, zero16, 0, 0, 0);
        a = __builtin_amdgcn_mfma_f32_32x32x16_bf16(uf0[g], b0, a, 0, 0, 0);
        a = __builtin_amdgcn_mfma_f32_32x32x16_bf16(uf1[g], b1, a, 0, 0, 0);
        acc[g] = a;
    }

    float pp = 0.0f;
    float he = 0.0f;                   // even-row h, packed on the odd row
#pragma unroll
    for (int r = 0; r < 16; ++r) {
        float ei = __builtin_amdgcn_exp2f(acc[0][r]);
        float ef = __builtin_amdgcn_exp2f(acc[1][r]);
        float eg = __builtin_amdgcn_exp2f(acc[2][r]);             // fmin dropped (R9)
        float eo = __builtin_amdgcn_exp2f(acc[3][r]);
        float di = 1.0f + ei, df = 1.0f + ef, dg = 1.0f + eg, do_ = 1.0f + eo;
        float ngs = __builtin_fmaf(eg, 2.0f * L2E, -2.0f * L2E);  // -2L2E*(1-eg)
        float t1 = di * dg;
        float t2 = cs[r] * t1;
        float num = __builtin_fmaf(ngs, df, t2);
        float cn = num * __builtin_amdgcn_rcpf(df * t1);          // scaled c'
        cs[r] = cn;
        float ec = __builtin_amdgcn_exp2f(__builtin_fminf(cn, ECLAMP)); // e^-2c
        float den = __builtin_fmaf(ec, do_, do_);                 // do*(1+ec)
        float inv = __builtin_amdgcn_rcpf(den);
        float h = __builtin_fmaf(-ec, inv, inv);                  // (1-ec)*inv
        if constexpr (NEED_P) pp = __builtin_fmaf(h, wq[r >> 2][r & 3], pp);
        if ((r & 1) == 0) {
            he = h;
        } else {
            unsigned d;  // low16 = bf16_rne(he) [even], high16 = bf16_rne(h) [odd]
            asm("v_cvt_pk_bf16_f32 %0, %1, %2" : "=v"(d) : "v"(he), "v"(h));
            const int q = r >> 1;      // compile-time after unroll
            if (q < 4) B0[q] = d;
            else       B1[q - 4] = d;
        }
    }
    return pp;
}

// (256,3): R10 measured 152 unified regs (88 arch + 64 AGPR) — fits the
// 3-waves/SIMD cap (512/3 ~= 170) with margin, so the (256,2) bound was
// over-conservative. Serial-issue model (6x confirmed R0-R10): total issued
// cycles are occupancy-invariant; the 3rd wave exists purely to fill the
// ~7% issue-gap residue (2307 vs 2152-cyc additive floor at 2 waves).
// Schedule: 768 blocks at 3/CU (packed) + 256-block tail at 1/CU — the
// tail is throughput-occupied (trans/MFMA per-instruction), so single-wave
// exposure is small now that no in-loop LDS reads exist (vs R0's tail).
__global__ __launch_bounds__(256, 3) void lstm_feedback_mfma24(
    const float* __restrict__ inputs,  // [B, 48]
    const float* __restrict__ Wk_w, const float* __restrict__ Uk_w, const float* __restrict__ b_w,
    const float* __restrict__ Wk_d, const float* __restrict__ Uk_d, const float* __restrict__ b_d,
    const float* __restrict__ Wd, const float* __restrict__ bd,
    float* __restrict__ out,           // [B, 24]
    int B) {
    const int tid = threadIdx.x;       // 4 waves x 32 batch = 128 batch/block
    const int w = tid >> 6;
    const int lane = tid & 63;
    const int m = lane & 31;           // batch column within wave / out-unit row
    const int H = lane >> 5;
    const int mblk = blockIdx.x * 128;
    const long row = (long)(mblk + w * 32 + m);

    __shared__ __align__(16) short uflds[16 * 64 * 8];  // 16 KB: both cells' hi U-frags

    // Waves 0/1 stage cell 0/1: hi U-frags (pre-scaled, permuted, RNE).
    if (w < 2) {
        const float* Uks = w ? Uk_d : Uk_w;
#pragma unroll
        for (int g = 0; g < 4; ++g) {
            const float s = gate_scale(g);
#pragma unroll
            for (int c = 0; c < 2; ++c) {
                bf16x8 ah;
#pragma unroll
                for (int j = 0; j < 8; ++j) {
                    const int uin = 16 * c + 4 * H + (j & 3) + 8 * (j >> 2);
                    float wt = Uks[uin * 128 + g * 32 + m] * s;
                    short hb, lb; bf_split_rne(wt, hb, lb);
                    ah[j] = hb;
                }
                *(bf16x8*)(uflds + (uslot(w, g, c) * 64 + lane) * 8) = ah;
            }
        }
    }

    const unsigned hmask = (H == 0) ? 0xFFFFFFFFu : 0u;

    // Wd in D-layout order, straight from global (L2-broadcast, one-time).
    f32x4 wq[4];
#pragma unroll
    for (int r = 0; r < 16; ++r)
        wq[r >> 2][r & 3] = Wd[(r & 3) + 8 * (r >> 2) + 4 * H];

    // Warmup cell's A4 in registers.
    bf16x8 a4[4];
    make_a4(Wk_w, b_w, m, H, a4);

    u32x4 z4 = {0u, 0u, 0u, 0u};
    u32x4 B0 = z4, B1 = z4;
    float cs[16];
#pragma unroll
    for (int r = 0; r < 16; ++r) cs[r] = 0.0f;

    __syncthreads();  // uflds visible

    // Hoist warmup-cell U-frags into registers (one-time; 8 ds_read_b128).
    bf16x8 uf0[4], uf1[4];
#pragma unroll
    for (int g = 0; g < 4; ++g) {
        uf0[g] = *(const bf16x8*)(uflds + (uslot(0, g, 0) * 64 + lane) * 8);
        uf1[g] = *(const bf16x8*)(uflds + (uslot(0, g, 1) * 64 + lane) * 8);
    }

    // ---- warmup: per-lane x from global (L2-resident), one-step prefetch ----
    float xc = inputs[row * TSTEPS + 0];
    for (int t = 0; t < TSTEPS - 1; ++t) {
        float xn = inputs[row * TSTEPS + t + 1];  // issued before the step body
        lstm_step32<false>(xc, uf0, uf1, a4, B0, B1, cs, wq, hmask);
        xc = xn;
    }

    const float bdv = bd[0];

    // ---- last warmup step with pred fold; single-shuffle reduce ----
    float p = lstm_step32<true>(xc, uf0, uf1, a4, B0, B1, cs, wq, hmask);
    p += __shfl_xor(p, 32);
    p += bdv;                          // both H lanes of batch m hold pred(batch m)
    if (H == 0) out[row * OUT_STEPS + 0] = p;

    // ---- transition: decode-cell operands into the same registers ----
    make_a4(Wk_d, b_d, m, H, a4);      // per-lane, global L2 (no barrier needed)
#pragma unroll
    for (int g = 0; g < 4; ++g) {      // uflds unchanged since staging barrier
        uf0[g] = *(const bf16x8*)(uflds + (uslot(1, g, 0) * 64 + lane) * 8);
        uf1[g] = *(const bf16x8*)(uflds + (uslot(1, g, 1) * 64 + lane) * 8);
    }

    // ---- decode ----
    for (int s = 1; s < OUT_STEPS; ++s) {
        p = lstm_step32<true>(p, uf0, uf1, a4, B0, B1, cs, wq, hmask);
        p += __shfl_xor(p, 32);
        p += bdv;
        if (H == 0) out[row * OUT_STEPS + s] = p;
    }
}

extern "C" void kernel_launch(void* const* d_in, const int* in_sizes, int n_in,
                              void* d_out, int out_size, void* d_ws, size_t ws_size,
                              hipStream_t stream) {
    const float* inputs = (const float*)d_in[0];
    const float* Wk_w   = (const float*)d_in[1];
    const float* Uk_w   = (const float*)d_in[2];
    const float* b_w    = (const float*)d_in[3];
    const float* Wk_d   = (const float*)d_in[4];
    const float* Uk_d   = (const float*)d_in[5];
    const float* b_d    = (const float*)d_in[6];
    const float* Wd     = (const float*)d_in[7];
    const float* bd     = (const float*)d_in[8];
    float* out = (float*)d_out;

    const int B = in_sizes[0] / TSTEPS;
    const int grid = (B + 127) / 128;  // 128 batch rows per 256-thread block
    lstm_feedback_mfma24<<<grid, 256, 0, stream>>>(
        inputs, Wk_w, Uk_w, b_w, Wk_d, Uk_d, b_d, Wd, bd, out, B);
}

// Round 12
// 311.992 us; speedup vs baseline: 1.0091x; 1.0091x over previous
//
#include <hip/hip_runtime.h>

#define TSTEPS 48
#define OUT_STEPS 24
#define L2E 1.44269504088896340736f
#define ECLAMP 30.0f

typedef short bf16x8 __attribute__((ext_vector_type(8)));
typedef float f32x16 __attribute__((ext_vector_type(16)));
typedef float f32x4 __attribute__((ext_vector_type(4)));
typedef unsigned int u32x4 __attribute__((ext_vector_type(4)));

// RNE bf16 hi + truncated-residual lo (weights; off hot path).
__device__ __forceinline__ void bf_split_rne(float f, short& hi, short& lo) {
    unsigned u = __builtin_bit_cast(unsigned, f);
    unsigned r = u + 0x7FFFu + ((u >> 16) & 1u);
    unsigned short hb = (unsigned short)(r >> 16);
    float hif = __builtin_bit_cast(float, (unsigned)hb << 16);
    float lof = f - hif;
    unsigned short lb = (unsigned short)(__builtin_bit_cast(unsigned, lof) >> 16);
    hi = (short)hb; lo = (short)lb;
}

// Gate pre-scale for exp2: i,f,o -> -log2e; g (gate 2) -> -2*log2e.
__device__ __forceinline__ float gate_scale(int g) {
    return (g == 2) ? (-2.0f * L2E) : (-L2E);
}

// U-frag LDS slot (hi-only): (cell*4+g)*2+c, addr (slot*64+lane)*16B.
__device__ __forceinline__ int uslot(int cell, int g, int c) {
    return (cell * 4 + g) * 2 + c;
}

// Per-lane A4 frags IN REGISTERS (R10-verified; no LDS roundtrip).
// Layout: [wk_hi, wk_lo, b_hi, b_lo, 0,0,0,0], B4 = [x,x,1,1].
__device__ __forceinline__ void make_a4(const float* __restrict__ Wks,
                                        const float* __restrict__ bvs,
                                        int m, int H, bf16x8* a4) {
#pragma unroll
    for (int g = 0; g < 4; ++g) {
        const float s = gate_scale(g);
        short whi, wlo, bhi, blo;
        bf_split_rne(Wks[g * 32 + m] * s, whi, wlo);
        bf_split_rne(bvs[g * 32 + m] * s, bhi, blo);
        bf16x8 a = {whi, wlo, bhi, blo, 0, 0, 0, 0};
        u32x4 z4 = {0u, 0u, 0u, 0u};
        if (H != 0) a = __builtin_bit_cast(bf16x8, z4);
        a4[g] = a;
    }
}

// One LSTM step for 32 batch rows. VERBATIM from R10/R11 (verified
// 4.88e-4). All operands register-resident; 12 MFMA: per gate A4*B4,
// Ah0*B0, Ah1*B1; h carried as RNE bf16 via cvt_pk.
template <bool NEED_P>
__device__ __forceinline__ float lstm_step32(float x,
    const bf16x8* __restrict__ uf0,   // [4] K-half 0 U-frags (regs)
    const bf16x8* __restrict__ uf1,   // [4] K-half 1 U-frags (regs)
    const bf16x8* __restrict__ a4,    // [4] Wk/b frags (regs)
    u32x4& B0, u32x4& B1,
    float* cs, const f32x4* __restrict__ wq,  // [4] Wd in D-reg order (regs)
    unsigned hmask) {
    // B4 on H==0 lanes: [x_rne, x_rne, 1, 1, 0,0,0,0].
    unsigned xr;
    asm("v_cvt_pk_bf16_f32 %0, %1, %2" : "=v"(xr) : "v"(x), "v"(x));
    unsigned w0 = xr & hmask;
    unsigned w1 = 0x3F803F80u & hmask;
    u32x4 b4u = {w0, w1, 0u, 0u};
    const bf16x8 B4 = __builtin_bit_cast(bf16x8, b4u);
    const bf16x8 b0 = __builtin_bit_cast(bf16x8, B0);
    const bf16x8 b1 = __builtin_bit_cast(bf16x8, B1);
    const f32x16 zero16 = {0,0,0,0,0,0,0,0,0,0,0,0,0,0,0,0};

    f32x16 acc[4];
#pragma unroll
    for (int g = 0; g < 4; ++g) {
        f32x16 a = __builtin_amdgcn_mfma_f32_32x32x16_bf16(a4[g], B4, zero16, 0, 0, 0);
        a = __builtin_amdgcn_mfma_f32_32x32x16_bf16(uf0[g], b0, a, 0, 0, 0);
        a = __builtin_amdgcn_mfma_f32_32x32x16_bf16(uf1[g], b1, a, 0, 0, 0);
        acc[g] = a;
    }

    float pp = 0.0f;
    float he = 0.0f;                   // even-row h, packed on the odd row
#pragma unroll
    for (int r = 0; r < 16; ++r) {
        float ei = __builtin_amdgcn_exp2f(acc[0][r]);
        float ef = __builtin_amdgcn_exp2f(acc[1][r]);
        float eg = __builtin_amdgcn_exp2f(acc[2][r]);             // fmin dropped (R9)
        float eo = __builtin_amdgcn_exp2f(acc[3][r]);
        float di = 1.0f + ei, df = 1.0f + ef, dg = 1.0f + eg, do_ = 1.0f + eo;
        float ngs = __builtin_fmaf(eg, 2.0f * L2E, -2.0f * L2E);  // -2L2E*(1-eg)
        float t1 = di * dg;
        float t2 = cs[r] * t1;
        float num = __builtin_fmaf(ngs, df, t2);
        float cn = num * __builtin_amdgcn_rcpf(df * t1);          // scaled c'
        cs[r] = cn;
        float ec = __builtin_amdgcn_exp2f(__builtin_fminf(cn, ECLAMP)); // e^-2c
        float den = __builtin_fmaf(ec, do_, do_);                 // do*(1+ec)
        float inv = __builtin_amdgcn_rcpf(den);
        float h = __builtin_fmaf(-ec, inv, inv);                  // (1-ec)*inv
        if constexpr (NEED_P) pp = __builtin_fmaf(h, wq[r >> 2][r & 3], pp);
        if ((r & 1) == 0) {
            he = h;
        } else {
            unsigned d;  // low16 = bf16_rne(he) [even], high16 = bf16_rne(h) [odd]
            asm("v_cvt_pk_bf16_f32 %0, %1, %2" : "=v"(d) : "v"(he), "v"(h));
            const int q = r >> 1;      // compile-time after unroll
            if (q < 4) B0[q] = d;
            else       B1[q - 4] = d;
        }
    }
    return pp;
}

// (256,3) SPILL-FREE: R11's counters showed the 3rd wave helped steady-state
// (270 vs 273 us) but cost a ~3-dword/thread scratch spill (WRITE_SIZE
// 12.3->15.2 MB) + a 366us cold dispatch (scratch first-touch). Cause: cap
// 512/3=170, AGPR 64 -> 106 arch; R10 working set 88 + wq 16 = 111 > 106.
// Fix: wq (Wd) is dead through all 47 warmup steps — load it AFTER the
// warmup loop (memory-clobber fence stops hoisting). Warmup-phase pressure
// ~95 < 106 -> no spill, no scratch, no cold-dispatch penalty.
__global__ __launch_bounds__(256, 3) void lstm_feedback_mfma25(
    const float* __restrict__ inputs,  // [B, 48]
    const float* __restrict__ Wk_w, const float* __restrict__ Uk_w, const float* __restrict__ b_w,
    const float* __restrict__ Wk_d, const float* __restrict__ Uk_d, const float* __restrict__ b_d,
    const float* __restrict__ Wd, const float* __restrict__ bd,
    float* __restrict__ out,           // [B, 24]
    int B) {
    const int tid = threadIdx.x;       // 4 waves x 32 batch = 128 batch/block
    const int w = tid >> 6;
    const int lane = tid & 63;
    const int m = lane & 31;           // batch column within wave / out-unit row
    const int H = lane >> 5;
    const int mblk = blockIdx.x * 128;
    const long row = (long)(mblk + w * 32 + m);

    __shared__ __align__(16) short uflds[16 * 64 * 8];  // 16 KB: both cells' hi U-frags

    // Waves 0/1 stage cell 0/1: hi U-frags (pre-scaled, permuted, RNE).
    if (w < 2) {
        const float* Uks = w ? Uk_d : Uk_w;
#pragma unroll
        for (int g = 0; g < 4; ++g) {
            const float s = gate_scale(g);
#pragma unroll
            for (int c = 0; c < 2; ++c) {
                bf16x8 ah;
#pragma unroll
                for (int j = 0; j < 8; ++j) {
                    const int uin = 16 * c + 4 * H + (j & 3) + 8 * (j >> 2);
                    float wt = Uks[uin * 128 + g * 32 + m] * s;
                    short hb, lb; bf_split_rne(wt, hb, lb);
                    ah[j] = hb;
                }
                *(bf16x8*)(uflds + (uslot(w, g, c) * 64 + lane) * 8) = ah;
            }
        }
    }

    const unsigned hmask = (H == 0) ? 0xFFFFFFFFu : 0u;

    // Warmup cell's A4 in registers.
    bf16x8 a4[4];
    make_a4(Wk_w, b_w, m, H, a4);

    u32x4 z4 = {0u, 0u, 0u, 0u};
    u32x4 B0 = z4, B1 = z4;
    float cs[16];
#pragma unroll
    for (int r = 0; r < 16; ++r) cs[r] = 0.0f;

    __syncthreads();  // uflds visible

    // Hoist warmup-cell U-frags into registers (one-time; 8 ds_read_b128).
    bf16x8 uf0[4], uf1[4];
#pragma unroll
    for (int g = 0; g < 4; ++g) {
        uf0[g] = *(const bf16x8*)(uflds + (uslot(0, g, 0) * 64 + lane) * 8);
        uf1[g] = *(const bf16x8*)(uflds + (uslot(0, g, 1) * 64 + lane) * 8);
    }

    // ---- warmup: per-lane x from global (L2-resident), one-step prefetch ----
    // wq is NOT live here (loaded after the loop) — keeps arch regs < 106.
    f32x4 wq[4];
    float xc = inputs[row * TSTEPS + 0];
    for (int t = 0; t < TSTEPS - 1; ++t) {
        float xn = inputs[row * TSTEPS + t + 1];  // issued before the step body
        lstm_step32<false>(xc, uf0, uf1, a4, B0, B1, cs, wq, hmask);
        xc = xn;
    }

    // Fence: stop the scheduler hoisting the wq/bd loads across the loop.
    asm volatile("" ::: "memory");

    // Wd in D-layout order, from global (L2-broadcast, once, post-warmup).
#pragma unroll
    for (int r = 0; r < 16; ++r)
        wq[r >> 2][r & 3] = Wd[(r & 3) + 8 * (r >> 2) + 4 * H];
    const float bdv = bd[0];

    // ---- last warmup step with pred fold; single-shuffle reduce ----
    float p = lstm_step32<true>(xc, uf0, uf1, a4, B0, B1, cs, wq, hmask);
    p += __shfl_xor(p, 32);
    p += bdv;                          // both H lanes of batch m hold pred(batch m)
    if (H == 0) out[row * OUT_STEPS + 0] = p;

    // ---- transition: decode-cell operands into the same registers ----
    make_a4(Wk_d, b_d, m, H, a4);      // per-lane, global L2 (no barrier needed)
#pragma unroll
    for (int g = 0; g < 4; ++g) {      // uflds unchanged since staging barrier
        uf0[g] = *(const bf16x8*)(uflds + (uslot(1, g, 0) * 64 + lane) * 8);
        uf1[g] = *(const bf16x8*)(uflds + (uslot(1, g, 1) * 64 + lane) * 8);
    }

    // ---- decode ----
    for (int s = 1; s < OUT_STEPS; ++s) {
        p = lstm_step32<true>(p, uf0, uf1, a4, B0, B1, cs, wq, hmask);
        p += __shfl_xor(p, 32);
        p += bdv;
        if (H == 0) out[row * OUT_STEPS + s] = p;
    }
}

extern "C" void kernel_launch(void* const* d_in, const int* in_sizes, int n_in,
                              void* d_out, int out_size, void* d_ws, size_t ws_size,
                              hipStream_t stream) {
    const float* inputs = (const float*)d_in[0];
    const float* Wk_w   = (const float*)d_in[1];
    const float* Uk_w   = (const float*)d_in[2];
    const float* b_w    = (const float*)d_in[3];
    const float* Wk_d   = (const float*)d_in[4];
    const float* Uk_d   = (const float*)d_in[5];
    const float* b_d    = (const float*)d_in[6];
    const float* Wd     = (const float*)d_in[7];
    const float* bd     = (const float*)d_in[8];
    float* out = (float*)d_out;

    const int B = in_sizes[0] / TSTEPS;
    const int grid = (B + 127) / 128;  // 128 batch rows per 256-thread block
    lstm_feedback_mfma25<<<grid, 256, 0, stream>>>(
        inputs, Wk_w, Uk_w, b_w, Wk_d, Uk_d, b_d, Wd, bd, out, B);
}